// Round 20
// baseline (102.863 us; speedup 1.0000x reference)
//
#include <hip/hip_runtime.h>

#define C 128
#define HID 256
#define MT 64       // nodes per block in mlp_mfma
#define EPB 2048    // edges per block in bucket_scatter
#define BSH 8       // nodes per bucket = 256
#define CAP 12288   // tmp records per bucket (mean 4096, sigma 64 -> safe)
#define OUTCAP (CAP + 2048)   // padded src_w capacity per bucket

typedef __attribute__((ext_vector_type(8))) short bf16x8;
typedef __attribute__((ext_vector_type(4))) short s16x4;
typedef __attribute__((ext_vector_type(4))) float f32x4;

__device__ inline unsigned short f2b(float f) {
    unsigned u = __builtin_bit_cast(unsigned, f);
    unsigned r = u + 0x7fffu + ((u >> 16) & 1u);
    return (unsigned short)(r >> 16);
}

// ---------- init: zero cursors + weight permute (128 blocks, cheap) ----------
// W-frag layout: lane l, elem j holds B[k][n]: n = nt*16+(l&15),
//                k = kk*32+16*(j>>2)+4*(l>>4)+(j&3)

__global__ __launch_bounds__(256) void init_k(
    const float* __restrict__ W1, const float* __restrict__ W2,
    unsigned short* __restrict__ W1p, unsigned short* __restrict__ W2p,
    int* __restrict__ cursor)
{
    const int bid = blockIdx.x;
    const int t = threadIdx.x;
    if (bid == 0) cursor[t] = 0;          // 256 >= NB
    int tt = bid * 256 + t;
    if (tt < C * HID) {
        {
            int j = tt & 7, l = (tt >> 3) & 63, kk = (tt >> 9) & 3, nt = tt >> 11;
            int n = nt * 16 + (l & 15);
            int k = kk * 32 + 16 * (j >> 2) + 4 * (l >> 4) + (j & 3);
            W1p[tt] = f2b(W1[k * HID + n]);
        }
        {
            int j = tt & 7, l = (tt >> 3) & 63, kk = (tt >> 9) & 7, nt = tt >> 12;
            int n = nt * 16 + (l & 15);
            int k = kk * 32 + 16 * (j >> 2) + 4 * (l >> 4) + (j & 3);
            W2p[tt] = f2b(W2[k * C + n]);
        }
    }
}

// ---------- scatter: LDS-stage edges, histogram, atomic-reserve, write ----------

__global__ __launch_bounds__(256) void bucket_scatter(
    const int* __restrict__ ei, const float* __restrict__ ea,
    int* __restrict__ cursor, uint2* __restrict__ tmp, int E, int NB)
{
    __shared__ unsigned recx[EPB];        // 8 KB
    __shared__ float    recw[EPB];        // 8 KB
    __shared__ unsigned char bkt[EPB];    // 2 KB
    __shared__ int bins[256];             // counts -> running cursor
    const int t = threadIdx.x;
    const int base = blockIdx.x * EPB;
    const int n = min(EPB, E - base);
    bins[t] = 0;
    __syncthreads();
    for (int i = t; i < n; i += 256) {
        int src = ei[base + i];
        int dst = ei[E + base + i];
        recx[i] = (unsigned)src | ((unsigned)(dst & 255) << 24);   // src < 2^24
        recw[i] = ea[base + i];
        int b = dst >> BSH;
        bkt[i] = (unsigned char)b;
        atomicAdd(&bins[b], 1);
    }
    __syncthreads();
    int myCount = bins[t];
    __syncthreads();
    int myBase = 0;
    if (t < NB && myCount > 0) myBase = atomicAdd(&cursor[t], myCount);
    bins[t] = t * CAP + myBase;           // running global cursor for bucket t
    __syncthreads();
    for (int i = t; i < n; i += 256) {
        int b = bkt[i];
        int pos = atomicAdd(&bins[b], 1);
        tmp[pos] = uint2{recx[i], __builtin_bit_cast(unsigned, recw[i])};
    }
}

// ---------- sort + x-convert fused (independent block ranges) ----------
// bid < NB: counting sort within bucket -> padded src_w, deg, offs.
// bid >= NB: x -> bf16 conversion (co-scheduled, hides convert time).

__global__ __launch_bounds__(256) void sort_xconv(
    const uint2* __restrict__ tmp, const int* __restrict__ cursor,
    uint2* __restrict__ src_w, int* __restrict__ deg_i, int* __restrict__ offs,
    const float* __restrict__ x, unsigned short* __restrict__ xb,
    long total4, int N, int NB)
{
    const int t = threadIdx.x;
    if ((int)blockIdx.x >= NB) {
        long i = (long)(blockIdx.x - NB) * 256 + t;
        if (i < total4) {
            float4 v = *(const float4*)(x + i * 4);
            ushort4 o;
            o.x = f2b(v.x); o.y = f2b(v.y); o.z = f2b(v.z); o.w = f2b(v.w);
            *(ushort4*)(xb + i * 4) = o;
        }
        return;
    }
    __shared__ int cnt[256];
    __shared__ int sc[256];
    const int b = blockIdx.x;
    const int s0 = b * CAP;
    const int s1 = s0 + cursor[b];
    const int pbase = b * OUTCAP;
    cnt[t] = 0;
    __syncthreads();
    for (int i = s0 + t; i < s1; i += 256)
        atomicAdd(&cnt[tmp[i].x >> 24], 1);
    __syncthreads();
    const int d = cnt[t];
    const int pd = (d + 7) & ~7;
    sc[t] = pd;
    __syncthreads();
    for (int off = 1; off < 256; off <<= 1) {
        int v = (t >= off) ? sc[t - off] : 0;
        __syncthreads();
        sc[t] += v;
        __syncthreads();
    }
    const int my_off = pbase + sc[t] - pd;   // exclusive padded position
    const int node = (b << BSH) + t;
    if (node < N) {
        deg_i[node] = d;
        offs[node]  = my_off;
    }
    cnt[t] = my_off;   // becomes cursor
    __syncthreads();
    for (int i = s0 + t; i < s1; i += 256) {
        uint2 r = tmp[i];
        int pos = atomicAdd(&cnt[r.x >> 24], 1);
        r.x &= 0x00ffffffu;
        src_w[pos] = r;
    }
    // fill pad slots with zero records (gathers hit hot row 0, weight 0)
    const uint2 zero{0u, 0u};
    for (int i = my_off + d; i < my_off + pd; ++i) src_w[i] = zero;
}

// ---------- per-node CSR aggregation (padded batch-16, no tail) ----------
// EXACT round-14 body: 4/4 validations at absmax 3.9e-3.

__global__ __launch_bounds__(512) void node_agg(
    const float* __restrict__ x, const unsigned short* __restrict__ xb,
    const int* __restrict__ offs, const int* __restrict__ deg_i,
    const uint2* __restrict__ src_w, unsigned short* __restrict__ out0, int N)
{
    const int lane = threadIdx.x & 63;
    const int wid  = threadIdx.x >> 6;          // 8 waves = 8 nodes per block
    const int node = blockIdx.x * 8 + wid;
    if (node >= N) return;
    const int rs = offs[node];
    const int d  = deg_i[node];
    const int pd = (d + 7) & ~7;                // segment is padded to this
    const int c  = lane * 2;
    float a0 = 0.f, a1 = 0.f;
    int j = 0;
    for (; j + 16 <= pd; j += 16) {
        uint2 e[16];
        #pragma unroll
        for (int i = 0; i < 16; ++i) e[i] = src_w[rs + j + i];
        unsigned v[16];
        #pragma unroll
        for (int i = 0; i < 16; ++i)
            v[i] = *(const unsigned*)(xb + (long)e[i].x * C + c);
        #pragma unroll
        for (int i = 0; i < 16; ++i) {
            float w = __builtin_bit_cast(float, e[i].y);
            a0 = fmaf(__builtin_bit_cast(float, v[i] << 16), w, a0);
            a1 = fmaf(__builtin_bit_cast(float, v[i] & 0xffff0000u), w, a1);
        }
    }
    if (j < pd) {   // exactly one batch-8 (pd % 16 == 8)
        uint2 e[8];
        #pragma unroll
        for (int i = 0; i < 8; ++i) e[i] = src_w[rs + j + i];
        unsigned v[8];
        #pragma unroll
        for (int i = 0; i < 8; ++i)
            v[i] = *(const unsigned*)(xb + (long)e[i].x * C + c);
        #pragma unroll
        for (int i = 0; i < 8; ++i) {
            float w = __builtin_bit_cast(float, e[i].y);
            a0 = fmaf(__builtin_bit_cast(float, v[i] << 16), w, a0);
            a1 = fmaf(__builtin_bit_cast(float, v[i] & 0xffff0000u), w, a1);
        }
    }
    float dd  = (d > 0) ? (float)d : 1.f;
    float inv = 1.f / dd;
    float2 xv = *(const float2*)(x + (long)node * C + c);
    float o0 = 0.5f * (xv.x + a0 * inv);
    float o1 = 0.5f * (xv.y + a1 * inv);
    unsigned pack = (unsigned)f2b(o0) | ((unsigned)f2b(o1) << 16);
    *(unsigned*)(out0 + (long)node * C + c) = pack;
}

// ---------- MFMA MLP (EXACT round-14 body) ----------

__global__ __launch_bounds__(256) void mlp_mfma(
    const unsigned short* __restrict__ out0,
    const unsigned short* __restrict__ W1p, const float* __restrict__ b1,
    const unsigned short* __restrict__ W2p, const float* __restrict__ b2,
    float* __restrict__ out, int N)
{
    __shared__ unsigned short hS[4][16][264];
    const int lane = threadIdx.x & 63;
    const int wid  = threadIdx.x >> 6;
    const int r16  = lane & 15;
    const int grp  = lane >> 4;
    const int nodeBase = blockIdx.x * MT + wid * 16;

    bf16x8 a1[4];
    {
        int arow = nodeBase + r16;
        if (arow >= N) arow = N - 1;
        const unsigned short* ar = out0 + (long)arow * C;
        #pragma unroll
        for (int kk = 0; kk < 4; ++kk) {
            s16x4 lo = *(const s16x4*)(ar + kk * 32 + 4 * grp);
            s16x4 hi = *(const s16x4*)(ar + kk * 32 + 16 + 4 * grp);
            bf16x8 a;
            a[0] = lo[0]; a[1] = lo[1]; a[2] = lo[2]; a[3] = lo[3];
            a[4] = hi[0]; a[5] = hi[1]; a[6] = hi[2]; a[7] = hi[3];
            a1[kk] = a;
        }
    }

    #pragma unroll 4
    for (int nt = 0; nt < 16; ++nt) {
        f32x4 acc = {0.f, 0.f, 0.f, 0.f};
        #pragma unroll
        for (int kk = 0; kk < 4; ++kk) {
            bf16x8 b = *(const bf16x8*)(W1p + (((nt * 4 + kk) * 64 + lane) << 3));
            acc = __builtin_amdgcn_mfma_f32_16x16x32_bf16(a1[kk], b, acc, 0, 0, 0);
        }
        float bias = b1[nt * 16 + r16];
        #pragma unroll
        for (int r = 0; r < 4; ++r) {
            float h = fmaxf(acc[r] + bias, 0.f);
            hS[wid][grp * 4 + r][nt * 16 + r16] = f2b(h);
        }
    }

    __syncthreads();

    bf16x8 a2[8];
    #pragma unroll
    for (int kk = 0; kk < 8; ++kk) {
        s16x4 lo = *(const s16x4*)&hS[wid][r16][kk * 32 + 4 * grp];
        s16x4 hi = *(const s16x4*)&hS[wid][r16][kk * 32 + 16 + 4 * grp];
        bf16x8 a;
        a[0] = lo[0]; a[1] = lo[1]; a[2] = lo[2]; a[3] = lo[3];
        a[4] = hi[0]; a[5] = hi[1]; a[6] = hi[2]; a[7] = hi[3];
        a2[kk] = a;
    }

    #pragma unroll 2
    for (int nt = 0; nt < 8; ++nt) {
        f32x4 acc = {0.f, 0.f, 0.f, 0.f};
        #pragma unroll
        for (int kk = 0; kk < 8; ++kk) {
            bf16x8 b = *(const bf16x8*)(W2p + (((nt * 8 + kk) * 64 + lane) << 3));
            acc = __builtin_amdgcn_mfma_f32_16x16x32_bf16(a2[kk], b, acc, 0, 0, 0);
        }
        float bias = b2[nt * 16 + r16];
        #pragma unroll
        for (int r = 0; r < 4; ++r) {
            int node = nodeBase + grp * 4 + r;
            if (node < N) out[(long)node * C + nt * 16 + r16] = acc[r] + bias;
        }
    }
}

extern "C" void kernel_launch(void* const* d_in, const int* in_sizes, int n_in,
                              void* d_out, int out_size, void* d_ws, size_t ws_size,
                              hipStream_t stream) {
    const float* x  = (const float*)d_in[0];
    const int*   ei = (const int*)d_in[1];
    const float* ea = (const float*)d_in[2];
    const float* W1 = (const float*)d_in[3];
    const float* b1 = (const float*)d_in[4];
    const float* W2 = (const float*)d_in[5];
    const float* b2 = (const float*)d_in[6];
    float* out = (float*)d_out;
    const int N = in_sizes[0] / C;
    const int E = in_sizes[2];

    const int NB   = (N + 255) >> BSH;           // buckets (<=256 for N<=65536)
    const int NBLK = (E + EPB - 1) / EPB;        // edge blocks

    // workspace layout (16B-aligned chunks)
    char* p = (char*)d_ws;
    auto alloc = [&](size_t bytes) { char* q = p; p += (bytes + 15) & ~(size_t)15; return q; };
    int* deg_i   = (int*)alloc((size_t)N * 4);
    int* offs    = (int*)alloc((size_t)N * 4);
    int* cursor  = (int*)alloc(256 * 4);
    uint2* src_w = (uint2*)alloc((size_t)NB * OUTCAP * 8);
    // out0 region doubles as tmp (tmp dead before node_agg writes out0)
    size_t tmp_bytes  = (size_t)NB * CAP * 8;
    size_t out0_bytes = (size_t)N * C * 2;
    char* out0_raw    = alloc(tmp_bytes > out0_bytes ? tmp_bytes : out0_bytes);
    unsigned short* out0 = (unsigned short*)out0_raw;
    uint2* tmp        = (uint2*)out0_raw;
    unsigned short* W1p = (unsigned short*)alloc((size_t)C * HID * 2);
    unsigned short* W2p = (unsigned short*)alloc((size_t)HID * C * 2);
    unsigned short* xb  = (unsigned short*)alloc((size_t)N * C * 2);

    const long total4 = ((long)N * C) / 4;
    const int xblocks = (int)((total4 + 255) / 256);
    const int wblocks = (C * HID + 255) / 256;

    init_k<<<wblocks, 256, 0, stream>>>(W1, W2, W1p, W2p, cursor);
    bucket_scatter<<<NBLK, 256, 0, stream>>>(ei, ea, cursor, tmp, E, NB);
    sort_xconv<<<NB + xblocks, 256, 0, stream>>>(
        tmp, cursor, src_w, deg_i, offs, x, xb, total4, N, NB);
    node_agg<<<(N + 7) / 8, 512, 0, stream>>>(x, xb, offs, deg_i, src_w, out0, N);
    mlp_mfma<<<(N + MT - 1) / MT, 256, 0, stream>>>(out0, W1p, b1, W2p, b2, out, N);
}